// Round 1
// baseline (279.119 us; speedup 1.0000x reference)
//
#include <hip/hip_runtime.h>

typedef unsigned short u16;
typedef __bf16 bf16x8 __attribute__((ext_vector_type(8)));
typedef float f32x4 __attribute__((ext_vector_type(4)));
typedef u16 u16x8 __attribute__((ext_vector_type(8)));
typedef u16 u16x4 __attribute__((ext_vector_type(4)));

#define DEV static __device__ __forceinline__

DEV u16 f2bf(float f) {
  unsigned u = __builtin_bit_cast(unsigned, f);
  u += 0x7fffu + ((u >> 16) & 1u);
  return (u16)(u >> 16);
}

// async global->LDS, 16B per lane; LDS dest must be linear (wave base + lane*16)
DEV void gld16(const void* g, void* l) {
  __builtin_amdgcn_global_load_lds((__attribute__((address_space(1))) void*)(g),
                                   (__attribute__((address_space(3))) void*)(l),
                                   16, 0, 0);
}

// ---------------- cast fp32 -> bf16 (no transpose) ----------------
__global__ __launch_bounds__(256) void k_cast(const float* __restrict__ in,
                                              u16* __restrict__ out, int n4) {
  int i = blockIdx.x * 256 + threadIdx.x;
  if (i >= n4) return;
  float4 v = ((const float4*)in)[i];
  u16x4 r = { f2bf(v.x), f2bf(v.y), f2bf(v.z), f2bf(v.w) };
  ((u16x4*)out)[i] = r;
}

// ---------------- cast + transpose: in[R][Cc] fp32 -> out[Cc][R] bf16 --------
__global__ __launch_bounds__(256) void k_transpose_cast(const float* __restrict__ in,
                                                        u16* __restrict__ out,
                                                        int R, int Cc) {
  __shared__ u16 tile[64][65];
  int r0 = blockIdx.x * 64, c0 = blockIdx.y * 64;
  int tid = threadIdx.x;
#pragma unroll
  for (int rr = 0; rr < 4; ++rr) {
    int r = rr * 16 + (tid >> 4);
    int c = (tid & 15) * 4;
    float4 v = *(const float4*)&in[(size_t)(r0 + r) * Cc + c0 + c];
    tile[r][c + 0] = f2bf(v.x); tile[r][c + 1] = f2bf(v.y);
    tile[r][c + 2] = f2bf(v.z); tile[r][c + 3] = f2bf(v.w);
  }
  __syncthreads();
#pragma unroll
  for (int rr = 0; rr < 2; ++rr) {
    int cr = rr * 32 + (tid >> 3);
    int rc = (tid & 7) * 8;
    u16x8 v;
#pragma unroll
    for (int j = 0; j < 8; ++j) v[j] = tile[rc + j][cr];
    *(u16x8*)&out[(size_t)(c0 + cr) * R + r0 + rc] = v;
  }
}

// -------- extract V from qkv and transpose: vt[b][h][d=64][t=1024] bf16 ------
__global__ __launch_bounds__(256) void k_vtrans(const u16* __restrict__ qkv,
                                                u16* __restrict__ vt) {
  __shared__ u16 tile[64][65];
  int bid = blockIdx.x;
  int b = bid >> 8, h = (bid >> 4) & 15, tt = bid & 15;
  int tid = threadIdx.x;
#pragma unroll
  for (int rr = 0; rr < 2; ++rr) {
    int tl = rr * 32 + (tid >> 3);
    int d0 = (tid & 7) * 8;
    u16x8 v = *(const u16x8*)&qkv[(size_t)(b * 1024 + tt * 64 + tl) * 3072 + 2048 + h * 64 + d0];
#pragma unroll
    for (int j = 0; j < 8; ++j) tile[tl][d0 + j] = v[j];
  }
  __syncthreads();
#pragma unroll
  for (int rr = 0; rr < 2; ++rr) {
    int d = rr * 32 + (tid >> 3);
    int t0 = (tid & 7) * 8;
    u16x8 v;
#pragma unroll
    for (int j = 0; j < 8; ++j) v[j] = tile[t0 + j][d];
    *(u16x8*)&vt[((size_t)(b * 16 + h) * 64 + d) * 1024 + tt * 64 + t0] = v;
  }
}

// ---------------- lambda_full scalar ----------------
__global__ void k_lambda(const float* lq1, const float* lq2,
                         const float* lk1, const float* lk2, float* out) {
  int i = threadIdx.x;
  float a = 0.f, b = 0.f;
  if (i < 32) { a = lq1[i] * lk1[i]; b = lq2[i] * lk2[i]; }
#pragma unroll
  for (int s = 1; s < 64; s <<= 1) { a += __shfl_xor(a, s); b += __shfl_xor(b, s); }
  if (i == 0) out[0] = __expf(a) - __expf(b) + 0.2f;
}

// ---------------- bf16 GEMM: C[M][N] = A[M][K] * Bt[N][K]^T ----------------
// 128x128 tile, BK=32, 4 waves (2x2), each wave 64x64 via 4x4 16x16x32 MFMA.
// LDS XOR-swizzle (16B octets) applied via pre-swizzled global source.
template <bool OUT_F32>
__global__ __launch_bounds__(256) void k_gemm(const u16* __restrict__ A,
                                              const u16* __restrict__ Bt,
                                              void* __restrict__ Cout,
                                              int M, int N, int K) {
  __shared__ __align__(16) u16 As[128 * 32];
  __shared__ __align__(16) u16 Bs[128 * 32];
  int tid = threadIdx.x;
  int nbn = N >> 7;
  int bm = blockIdx.x / nbn, bn = blockIdx.x % nbn;
  int m0 = bm << 7, n0 = bn << 7;
  int lane = tid & 63, w = tid >> 6, wm = w >> 1, wn = w & 1;
  int lr = lane & 15, lg = lane >> 4;
  f32x4 acc[4][4] = {};
  for (int kt = 0; kt < K; kt += 32) {
#pragma unroll
    for (int rr = 0; rr < 2; ++rr) {
      int i = rr * 256 + tid;
      int r = i >> 2, c8 = i & 3;
      int s8 = c8 ^ ((r >> 1) & 3);
      gld16(&A[(size_t)(m0 + r) * K + kt + s8 * 8], &As[i * 8]);
    }
#pragma unroll
    for (int rr = 0; rr < 2; ++rr) {
      int i = rr * 256 + tid;
      int r = i >> 2, c8 = i & 3;
      int s8 = c8 ^ ((r >> 1) & 3);
      gld16(&Bt[(size_t)(n0 + r) * K + kt + s8 * 8], &Bs[i * 8]);
    }
    __syncthreads();
    bf16x8 af[4], bfr[4];
#pragma unroll
    for (int m = 0; m < 4; ++m) {
      int r = wm * 64 + m * 16 + lr;
      int c8 = lg ^ ((r >> 1) & 3);
      af[m] = *(const bf16x8*)&As[r * 32 + c8 * 8];
    }
#pragma unroll
    for (int n = 0; n < 4; ++n) {
      int r = wn * 64 + n * 16 + lr;
      int c8 = lg ^ ((r >> 1) & 3);
      bfr[n] = *(const bf16x8*)&Bs[r * 32 + c8 * 8];
    }
#pragma unroll
    for (int m = 0; m < 4; ++m)
#pragma unroll
      for (int n = 0; n < 4; ++n)
        acc[m][n] = __builtin_amdgcn_mfma_f32_16x16x32_bf16(af[m], bfr[n], acc[m][n], 0, 0, 0);
    __syncthreads();
  }
#pragma unroll
  for (int m = 0; m < 4; ++m)
#pragma unroll
    for (int r = 0; r < 4; ++r) {
      int gr = m0 + wm * 64 + m * 16 + lg * 4 + r;
#pragma unroll
      for (int n = 0; n < 4; ++n) {
        int gc = n0 + wn * 64 + n * 16 + lr;
        if (OUT_F32) ((float*)Cout)[(size_t)gr * N + gc] = acc[m][n][r];
        else ((u16*)Cout)[(size_t)gr * N + gc] = f2bf(acc[m][n][r]);
      }
    }
}

// ---------------- differential flash attention ----------------
// grid: 1024 blocks = (b:4, h:16, qblock:16); 4 waves x 16 q-rows; k-tiles of 64.
__global__ __launch_bounds__(256) void k_diffattn(const u16* __restrict__ qkv,
                                                  const u16* __restrict__ vt,
                                                  const float* __restrict__ lam_p,
                                                  const float* __restrict__ gamma,
                                                  u16* __restrict__ attn_out) {
  __shared__ __align__(16) u16 Ks[2][64 * 32];
  __shared__ __align__(16) u16 Vs[64 * 64];
  __shared__ __align__(16) u16 Ps[4][2][16 * 72];  // stride 72: conflict-free reads
  int bid = blockIdx.x;
  int b = bid >> 8, h = (bid >> 4) & 15, qb = bid & 15;
  int q0 = qb * 64;
  int tid = threadIdx.x, lane = tid & 63, w = tid >> 6;
  int lr = lane & 15, lg = lane >> 4;
  int g1 = 2 * h, g2 = g1 + 1;

  size_t qrow = (size_t)(b * 1024 + q0 + w * 16 + lr);
  bf16x8 qf1 = *(const bf16x8*)&qkv[qrow * 3072 + g1 * 32 + lg * 8];
  bf16x8 qf2 = *(const bf16x8*)&qkv[qrow * 3072 + g2 * 32 + lg * 8];

  f32x4 o1[4] = {}, o2[4] = {};
  float m1[4], l1[4], m2[4], l2[4];
#pragma unroll
  for (int r = 0; r < 4; ++r) { m1[r] = m2[r] = -1e30f; l1[r] = l2[r] = 0.f; }

  int ntiles = qb + 1;
  for (int t = 0; t < ntiles; ++t) {
    int s0 = t * 64;
    {  // stage K1,K2 (one round each)
      int i = tid, r = i >> 2, c8 = i & 3;
      int s8 = c8 ^ ((r >> 1) & 3);
      size_t krow = (size_t)(b * 1024 + s0 + r) * 3072 + 1024;
      gld16(&qkv[krow + g1 * 32 + s8 * 8], &Ks[0][i * 8]);
      gld16(&qkv[krow + g2 * 32 + s8 * 8], &Ks[1][i * 8]);
    }
#pragma unroll
    for (int rr = 0; rr < 2; ++rr) {  // stage V^T (2 rounds)
      int i = rr * 256 + tid;
      int d = i >> 3, o = (i & 7) ^ (d & 7);
      gld16(&vt[((size_t)((b * 16 + h) * 64 + d)) * 1024 + s0 + o * 8], &Vs[i * 8]);
    }
    __syncthreads();

    bool diag = (s0 == q0);
    f32x4 zero = {0.f, 0.f, 0.f, 0.f};
    f32x4 s1[4], s2[4];
#pragma unroll
    for (int ni = 0; ni < 4; ++ni) {
      int r = ni * 16 + lr;
      int c8 = lg ^ ((r >> 1) & 3);
      bf16x8 kf1 = *(const bf16x8*)&Ks[0][r * 32 + c8 * 8];
      bf16x8 kf2 = *(const bf16x8*)&Ks[1][r * 32 + c8 * 8];
      s1[ni] = __builtin_amdgcn_mfma_f32_16x16x32_bf16(qf1, kf1, zero, 0, 0, 0);
      s2[ni] = __builtin_amdgcn_mfma_f32_16x16x32_bf16(qf2, kf2, zero, 0, 0, 0);
    }

    auto smax = [&](f32x4* s, float* m, float* l, f32x4* o, u16* P) {
      float pv[4][4];
#pragma unroll
      for (int ni = 0; ni < 4; ++ni)
#pragma unroll
        for (int r = 0; r < 4; ++r) {
          float v = s[ni][r] * 0.03125f;
          if (diag) {
            int sg = s0 + ni * 16 + lr;
            int qg = q0 + w * 16 + lg * 4 + r;
            if (sg > qg) v = -1e30f;
          }
          pv[ni][r] = v;
        }
#pragma unroll
      for (int r = 0; r < 4; ++r) {
        float mx = fmaxf(fmaxf(pv[0][r], pv[1][r]), fmaxf(pv[2][r], pv[3][r]));
        mx = fmaxf(mx, __shfl_xor(mx, 1));
        mx = fmaxf(mx, __shfl_xor(mx, 2));
        mx = fmaxf(mx, __shfl_xor(mx, 4));
        mx = fmaxf(mx, __shfl_xor(mx, 8));
        float mn = fmaxf(m[r], mx);
        float alpha = __expf(m[r] - mn);
        m[r] = mn;
        l[r] *= alpha;
#pragma unroll
        for (int ni = 0; ni < 4; ++ni) o[ni][r] *= alpha;
        float rs = 0.f;
#pragma unroll
        for (int ni = 0; ni < 4; ++ni) {
          float p = __expf(pv[ni][r] - mn);
          rs += p;
          P[(lg * 4 + r) * 72 + ni * 16 + lr] = f2bf(p);
        }
        rs += __shfl_xor(rs, 1); rs += __shfl_xor(rs, 2);
        rs += __shfl_xor(rs, 4); rs += __shfl_xor(rs, 8);
        l[r] += rs;
      }
    };
    smax(s1, m1, l1, o1, &Ps[w][0][0]);
    smax(s2, m2, l2, o2, &Ps[w][1][0]);

#pragma unroll
    for (int kk = 0; kk < 2; ++kk) {
      bf16x8 pa1 = *(const bf16x8*)&Ps[w][0][lr * 72 + kk * 32 + lg * 8];
      bf16x8 pa2 = *(const bf16x8*)&Ps[w][1][lr * 72 + kk * 32 + lg * 8];
#pragma unroll
      for (int ni = 0; ni < 4; ++ni) {
        int d = ni * 16 + lr;
        int c8 = (kk * 4 + lg) ^ (d & 7);
        bf16x8 vb = *(const bf16x8*)&Vs[d * 64 + c8 * 8];
        o1[ni] = __builtin_amdgcn_mfma_f32_16x16x32_bf16(pa1, vb, o1[ni], 0, 0, 0);
        o2[ni] = __builtin_amdgcn_mfma_f32_16x16x32_bf16(pa2, vb, o2[ni], 0, 0, 0);
      }
    }
    __syncthreads();
  }

  float lam = *lam_p;
  float inv1[4], inv2[4];
#pragma unroll
  for (int r = 0; r < 4; ++r) { inv1[r] = 1.f / l1[r]; inv2[r] = 1.f / l2[r]; }
  float val[4][4];
#pragma unroll
  for (int ni = 0; ni < 4; ++ni)
#pragma unroll
    for (int r = 0; r < 4; ++r)
      val[ni][r] = o1[ni][r] * inv1[r] - lam * (o2[ni][r] * inv2[r]);
#pragma unroll
  for (int r = 0; r < 4; ++r) {
    float ss = 0.f;
#pragma unroll
    for (int ni = 0; ni < 4; ++ni) ss += val[ni][r] * val[ni][r];
    ss += __shfl_xor(ss, 1); ss += __shfl_xor(ss, 2);
    ss += __shfl_xor(ss, 4); ss += __shfl_xor(ss, 8);
    float sc = rsqrtf(ss * (1.f / 64.f) + 1e-5f) * 0.8f;
#pragma unroll
    for (int ni = 0; ni < 4; ++ni) val[ni][r] *= sc;
  }
#pragma unroll
  for (int ni = 0; ni < 4; ++ni) {
    int d = ni * 16 + lr;
    float g = gamma[d];
#pragma unroll
    for (int r = 0; r < 4; ++r) {
      int trow = q0 + w * 16 + lg * 4 + r;
      attn_out[(size_t)(b * 1024 + trow) * 1024 + h * 64 + d] = f2bf(val[ni][r] * g);
    }
  }
}

// ---------------- launch ----------------
extern "C" void kernel_launch(void* const* d_in, const int* in_sizes, int n_in,
                              void* d_out, int out_size, void* d_ws, size_t ws_size,
                              hipStream_t stream) {
  const float* x   = (const float*)d_in[0];
  const float* wa  = (const float*)d_in[1];
  const float* wp  = (const float*)d_in[2];
  const float* lq1 = (const float*)d_in[3];
  const float* lq2 = (const float*)d_in[4];
  const float* lk1 = (const float*)d_in[5];
  const float* lk2 = (const float*)d_in[6];
  const float* gam = (const float*)d_in[7];
  float* out = (float*)d_out;

  char* ws = (char*)d_ws;
  u16* xb   = (u16*)(ws);                        // 8 MiB  [4096][1024]
  u16* wab  = (u16*)(ws + (8ull << 20));         // 6 MiB  [3072][1024] (w_attn^T)
  u16* wpb  = (u16*)(ws + (14ull << 20));        // 2 MiB  [1024][1024] (w_proj^T)
  u16* qkv  = (u16*)(ws + (16ull << 20));        // 24 MiB [4096][3072]
  u16* vt   = (u16*)(ws + (40ull << 20));        // 8 MiB  [4][16][64][1024]
  u16* aout = (u16*)(ws + (48ull << 20));        // 8 MiB  [4096][1024]
  float* lam = (float*)(ws + (56ull << 20));     // 4 B

  k_cast<<<4096, 256, 0, stream>>>(x, xb, 1024 * 1024);
  k_transpose_cast<<<dim3(16, 48), 256, 0, stream>>>(wa, wab, 1024, 3072);
  k_transpose_cast<<<dim3(16, 16), 256, 0, stream>>>(wp, wpb, 1024, 1024);
  k_lambda<<<1, 64, 0, stream>>>(lq1, lq2, lk1, lk2, lam);
  k_gemm<false><<<32 * 24, 256, 0, stream>>>(xb, wab, qkv, 4096, 3072, 1024);
  k_vtrans<<<1024, 256, 0, stream>>>(qkv, vt);
  k_diffattn<<<1024, 256, 0, stream>>>(qkv, vt, lam, gam, aout);
  k_gemm<true><<<32 * 8, 256, 0, stream>>>(aout, wpb, out, 4096, 1024, 1024);
}